// Round 12
// baseline (90.712 us; speedup 1.0000x reference)
//
#include <hip/hip_runtime.h>
#include <stdint.h>

// Group / KNN: B=16, N=16384, NUM_GROUP=512, GROUP_SIZE=32.
// d_out = neighborhood [16][512][32][3] ++ center [16][512][3] ++ ids [16][512]
//
// r12 = r11 (GB=8 groups/block, direct global reads, no hot-path barriers,
// u64 counting-sort ranking) with the threshold pass shrunk from a FULL scan
// to a 16-pt/thread SAMPLE scan (points 0..8191), and the per-wave 64-lane
// bitonic replaced by fold-to-16-quad-mins + 16-element bitonic:
//   m_q = min over thread's 16 sample pts; fold xor16,xor32 -> quad-mins
//   (16 distinct values, replicated x4); 10-stage bitonic; lane 3 = 4th
//   smallest quad-min; T_q = max over 8 waves.
// Guarantee (deterministic): each wave has >=4 distinct quads with min <= T
// -> >=4 distinct SAMPLE points (real points) <= T -> >=32 per block, so the
// collected set is a superset of the true top-32. E[cnt]~100-130,
// P(cnt>CAP=384) ~ 1e-5/launch; exact wave-parallel fallback kept.
// Scoring unchanged from r10/r11: s = fma(n2c,x, xs) (rank == |x-c|^2);
// exact ranking of an exact superset -> output bit-identical to r11
// (absmax canary: 0.4521484).

#define TB     512
#define GB     8                  // groups per block
#define NCHUNK 32                 // 16384 / TB
#define SAMP   16                 // sample chunks (first 8192 points)
#define NWAVE  (TB / 64)          // 8
#define CAP    384                // per-group candidate capacity

__global__ __launch_bounds__(TB) void group_knn_kernel(
    const float* __restrict__ xyz,   // [16][16384][3]
    float* __restrict__ out_nb,      // [16][512][32][3]
    float* __restrict__ out_ctr,     // [16][512][3]
    float* __restrict__ out_ids)     // [16][512]
{
    const int NPTS = 16384;
    const int GSZ  = 32;

    const int blk = blockIdx.x;            // 0 .. 1023
    const int b   = blk >> 6;              // 64 blocks per batch
    const int g0  = (blk & 63) * GB;       // first group of this block
    const int t   = threadIdx.x;
    const int lane = t & 63;
    const int w    = t >> 6;

    const float* base = xyz + (size_t)b * NPTS * 3;

    // Per-group constants (block-uniform; L1-broadcast loads).
    float n2c0[GB], n2c1[GB], n2c2[GB];
#pragma unroll
    for (int q = 0; q < GB; ++q) {
        const int nc = (g0 + q) * 32;
        n2c0[q] = -2.0f * base[nc * 3 + 0];
        n2c1[q] = -2.0f * base[nc * 3 + 1];
        n2c2[q] = -2.0f * base[nc * 3 + 2];
    }

    __shared__ unsigned long long s_cand[GB][CAP];     // 24576 B
    __shared__ float s_t[GB][NWAVE];                   //   256 B
    __shared__ int s_cnt[GB];                          //    32 B
    __shared__ unsigned s_win[GB][GSZ];                //  1024 B

    // ---- Sample pass: per-thread min over 16 sample points --------------
    float m[GB];
#pragma unroll
    for (int q = 0; q < GB; ++q) m[q] = __builtin_inff();

    for (int i = 0; i < SAMP; i += 4) {
        float px[4][3];
#pragma unroll
        for (int u = 0; u < 4; ++u) {
            const int n = (i + u) * TB + t;
            const float* p = base + (size_t)n * 3;
            px[u][0] = p[0]; px[u][1] = p[1]; px[u][2] = p[2];
        }
#pragma unroll
        for (int u = 0; u < 4; ++u) {
            const float x0 = px[u][0], x1 = px[u][1], x2 = px[u][2];
            const float xs = __builtin_fmaf(x2, x2, __builtin_fmaf(x1, x1, x0 * x0));
#pragma unroll
            for (int q = 0; q < GB; ++q) {
                const float s = __builtin_fmaf(n2c0[q], x0,
                                __builtin_fmaf(n2c1[q], x1,
                                __builtin_fmaf(n2c2[q], x2, xs)));
                m[q] = fminf(m[q], s);
            }
        }
    }

    // ---- Thresholds: fold to 16 quad-mins, 16-elem bitonic, lane3 -------
#pragma unroll
    for (int q = 0; q < GB; ++q) {
        float v = m[q];
        v = fminf(v, __shfl_xor(v, 16, 64));
        v = fminf(v, __shfl_xor(v, 32, 64));   // quad-min, replicated x4
#pragma unroll
        for (int k = 2; k <= 16; k <<= 1) {
#pragma unroll
            for (int j = k >> 1; j > 0; j >>= 1) {
                const float o = __shfl_xor(v, j, 64);
                const bool up = ((lane & k) == 0);
                const bool takeMin = (((lane & j) == 0) == up);
                const float mn = fminf(v, o);
                const float mx = fmaxf(v, o);
                v = takeMin ? mn : mx;
            }
        }
        if (lane == 3) s_t[q][w] = v;    // 4th-smallest quad-min of this wave
    }
    if (t < GB) s_cnt[t] = 0;
    __syncthreads();                                   // barrier 1

    float T[GB];
#pragma unroll
    for (int q = 0; q < GB; ++q) {
        float Tq = s_t[q][0];
#pragma unroll
        for (int ww = 1; ww < NWAVE; ++ww) Tq = fmaxf(Tq, s_t[q][ww]);
        T[q] = Tq;
    }

    // ---- Single full scan: collect keys for s <= T_g --------------------
    for (int i = 0; i < NCHUNK; i += 4) {
        float px[4][3];
#pragma unroll
        for (int u = 0; u < 4; ++u) {
            const int n = (i + u) * TB + t;
            const float* p = base + (size_t)n * 3;
            px[u][0] = p[0]; px[u][1] = p[1]; px[u][2] = p[2];
        }
#pragma unroll
        for (int u = 0; u < 4; ++u) {
            const int n = (i + u) * TB + t;
            const float x0 = px[u][0], x1 = px[u][1], x2 = px[u][2];
            const float xs = __builtin_fmaf(x2, x2, __builtin_fmaf(x1, x1, x0 * x0));
#pragma unroll
            for (int q = 0; q < GB; ++q) {
                const float s = __builtin_fmaf(n2c0[q], x0,
                                __builtin_fmaf(n2c1[q], x1,
                                __builtin_fmaf(n2c2[q], x2, xs)));
                if (s <= T[q]) {
                    unsigned uu = __float_as_uint(s);
                    uu ^= (unsigned)(((int)uu) >> 31) | 0x80000000u;
                    const int pos = atomicAdd(&s_cnt[q], 1);
                    if (pos < CAP)
                        s_cand[q][pos] = ((unsigned long long)uu << 32) | (unsigned)n;
                }
            }
        }
    }
    __syncthreads();                                   // barrier 2

    // ---- Ranking: wave w handles group w --------------------------------
    {
        const int q = w;
        const int cnt = s_cnt[q];
        if (cnt <= CAP) {
            // counting sort (keys unique; broadcast inner reads)
            for (int j = lane; j < cnt; j += 64) {
                const unsigned long long c = s_cand[q][j];
                int r = 0;
                for (int i = 0; i < cnt; ++i) r += (s_cand[q][i] < c) ? 1 : 0;
                if (r < GSZ) s_win[q][r] = (unsigned)c & 0xFFFFu;
            }
        } else {
            // Wave-parallel exact fallback (cnt>CAP; ~1e-5 per launch).
            unsigned long long last = 0ull;
            for (int k = 0; k < GSZ; ++k) {
                unsigned long long best = ~0ull;
                for (int n = lane; n < NPTS; n += 64) {
                    const float x0 = base[n * 3 + 0];
                    const float x1 = base[n * 3 + 1];
                    const float x2 = base[n * 3 + 2];
                    const float xs = __builtin_fmaf(x2, x2,
                                     __builtin_fmaf(x1, x1, x0 * x0));
                    const float s = __builtin_fmaf(n2c0[q], x0,
                                    __builtin_fmaf(n2c1[q], x1,
                                    __builtin_fmaf(n2c2[q], x2, xs)));
                    unsigned uu = __float_as_uint(s);
                    uu ^= (unsigned)(((int)uu) >> 31) | 0x80000000u;
                    const unsigned long long kk =
                        ((unsigned long long)uu << 32) | (unsigned)n;
                    if (kk > last && kk < best) best = kk;
                }
#pragma unroll
                for (int mm = 32; mm >= 1; mm >>= 1) {
                    const unsigned long long o = __shfl_xor(best, mm, 64);
                    best = (o < best) ? o : best;
                }
                last = best;
                if (lane == 0) s_win[q][k] = (unsigned)best & 0xFFFFu;
            }
        }
    }
    __syncthreads();                                   // barrier 3

    // ---- Outputs --------------------------------------------------------
    const int gbase = b * 512 + g0;
    if (t < GB * GSZ) {                       // 256 threads: neighborhoods
        const int q  = t >> 5;
        const int tt = t & 31;
        const int nc = (g0 + q) * 32;
        const float cc0 = base[nc * 3 + 0];
        const float cc1 = base[nc * 3 + 1];
        const float cc2 = base[nc * 3 + 2];
        const unsigned n = s_win[q][tt];
        const float x0 = base[n * 3 + 0];
        const float x1 = base[n * 3 + 1];
        const float x2 = base[n * 3 + 2];
        const size_t ob = (((size_t)(gbase + q)) * GSZ + tt) * 3;
        out_nb[ob + 0] = x0 - cc0;
        out_nb[ob + 1] = x1 - cc1;
        out_nb[ob + 2] = x2 - cc2;
    } else if (t < GB * GSZ + GB * 3) {       // 24 threads: centers
        const int u = t - GB * GSZ;
        const int q = u / 3, c = u % 3;
        out_ctr[(size_t)(gbase + q) * 3 + c] = base[((g0 + q) * 32) * 3 + c];
    } else if (t < GB * GSZ + GB * 3 + GB) {  // 8 threads: ids
        const int q = t - (GB * GSZ + GB * 3);
        out_ids[gbase + q] = (float)((g0 + q) * 32);
    }
}

extern "C" void kernel_launch(void* const* d_in, const int* in_sizes, int n_in,
                              void* d_out, int out_size, void* d_ws, size_t ws_size,
                              hipStream_t stream) {
    const float* xyz = (const float*)d_in[0];
    float* out = (float*)d_out;
    float* out_nb  = out;                        // 786432
    float* out_ctr = out + 786432;               // 24576
    float* out_ids = out + 786432 + 24576;       // 8192
    hipLaunchKernelGGL(group_knn_kernel, dim3(16 * 512 / GB), dim3(TB), 0, stream,
                       xyz, out_nb, out_ctr, out_ids);
}

// Round 13
// 73.041 us; speedup vs baseline: 1.2419x; 1.2419x over previous
//
#include <hip/hip_runtime.h>
#include <stdint.h>

// Group / KNN: B=16, N=16384, NUM_GROUP=512, GROUP_SIZE=32.
// d_out = neighborhood [16][512][32][3] ++ center [16][512][3] ++ ids [16][512]
//
// r13 = r11 (best, 76 us: GB=8 groups/block, direct global dwordx3 reads,
// no hot-path barriers, full-scan pass A for tight thresholds, u64
// counting-sort ranking, CAP=224) with the group-inner dot products
// processed as f32x2 PAIRS to engage gfx950's packed fp32 VALU
// (v_pk_fma_f32: 2 FMAs/instr). s = C0*X0 + (C1*X1 + (C2*X2 + XS)) with
// default -ffp-contract=fast contracts to the same fma association as
// r11's scalar chain -> scores bit-identical -> absmax canary 0.4521484.
// r12's sample-threshold experiment reverted (cut evals 25%, dur +20%:
// looser T doubled candidates; eval count is not the binding constraint).

#define TB     512
#define GB     8                  // groups per block
#define PPT    32                 // points per thread = 16384/TB
#define NWAVE  (TB / 64)          // 8
#define CAP    224                // per-group candidate capacity

typedef __attribute__((ext_vector_type(2))) float f32x2;

__global__ __launch_bounds__(TB) void group_knn_kernel(
    const float* __restrict__ xyz,   // [16][16384][3]
    float* __restrict__ out_nb,      // [16][512][32][3]
    float* __restrict__ out_ctr,     // [16][512][3]
    float* __restrict__ out_ids)     // [16][512]
{
    const int NPTS = 16384;
    const int GSZ  = 32;

    const int blk = blockIdx.x;            // 0 .. 1023
    const int b   = blk >> 6;              // 64 blocks per batch
    const int g0  = (blk & 63) * GB;       // first group of this block
    const int t   = threadIdx.x;
    const int lane = t & 63;
    const int w    = t >> 6;

    const float* base = xyz + (size_t)b * NPTS * 3;

    // Per-group-pair constants (block-uniform; L1-broadcast loads).
    f32x2 C0[GB / 2], C1[GB / 2], C2[GB / 2];
#pragma unroll
    for (int p = 0; p < GB / 2; ++p) {
        const int ncA = (g0 + 2 * p) * 32;
        const int ncB = (g0 + 2 * p + 1) * 32;
        C0[p] = (f32x2){ -2.0f * base[ncA * 3 + 0], -2.0f * base[ncB * 3 + 0] };
        C1[p] = (f32x2){ -2.0f * base[ncA * 3 + 1], -2.0f * base[ncB * 3 + 1] };
        C2[p] = (f32x2){ -2.0f * base[ncA * 3 + 2], -2.0f * base[ncB * 3 + 2] };
    }

    __shared__ unsigned long long s_cand[GB][CAP];     // 14336 B
    __shared__ float s_t[GB][NWAVE];                   //   256 B
    __shared__ int s_cnt[GB];                          //    32 B
    __shared__ unsigned s_win[GB][GSZ];                //  1024 B

    // ---- Pass A: per-thread f32x2 min per group pair (direct reads) -----
    f32x2 m2[GB / 2];
#pragma unroll
    for (int p = 0; p < GB / 2; ++p)
        m2[p] = (f32x2){ __builtin_inff(), __builtin_inff() };

    for (int i = 0; i < PPT; i += 4) {
        float px[4][3];
#pragma unroll
        for (int u = 0; u < 4; ++u) {              // 4 dwordx3 loads in flight
            const int n = (i + u) * TB + t;
            const float* p = base + (size_t)n * 3;
            px[u][0] = p[0]; px[u][1] = p[1]; px[u][2] = p[2];
        }
#pragma unroll
        for (int u = 0; u < 4; ++u) {
            const float x0 = px[u][0], x1 = px[u][1], x2 = px[u][2];
            const float xs = __builtin_fmaf(x2, x2, __builtin_fmaf(x1, x1, x0 * x0));
            const f32x2 X0 = (f32x2){ x0, x0 };
            const f32x2 X1 = (f32x2){ x1, x1 };
            const f32x2 X2 = (f32x2){ x2, x2 };
            const f32x2 XS = (f32x2){ xs, xs };
#pragma unroll
            for (int p = 0; p < GB / 2; ++p) {
                const f32x2 s = C0[p] * X0 + (C1[p] * X1 + (C2[p] * X2 + XS));
                m2[p] = __builtin_elementwise_min(m2[p], s);
            }
        }
    }

    // ---- Thresholds: per-wave float bitonic; T_g = max of 4th-smallest --
#pragma unroll
    for (int q = 0; q < GB; ++q) {
        float v = (q & 1) ? m2[q >> 1].y : m2[q >> 1].x;
#pragma unroll
        for (int k = 2; k <= 64; k <<= 1) {
#pragma unroll
            for (int j = k >> 1; j > 0; j >>= 1) {
                const float o = __shfl_xor(v, j, 64);
                const bool up = ((lane & k) == 0);
                const bool takeMin = (((lane & j) == 0) == up);
                const float mn = fminf(v, o);
                const float mx = fmaxf(v, o);
                v = takeMin ? mn : mx;
            }
        }
        if (lane == 3) s_t[q][w] = v;    // 4th smallest in this wave
    }
    if (t < GB) s_cnt[t] = 0;
    __syncthreads();                                   // barrier 1

    f32x2 T2[GB / 2];
#pragma unroll
    for (int p = 0; p < GB / 2; ++p) {
        float Ta = s_t[2 * p][0], Tb = s_t[2 * p + 1][0];
#pragma unroll
        for (int ww = 1; ww < NWAVE; ++ww) {
            Ta = fmaxf(Ta, s_t[2 * p][ww]);
            Tb = fmaxf(Tb, s_t[2 * p + 1][ww]);
        }
        T2[p] = (f32x2){ Ta, Tb };
    }

    // ---- Pass B: recompute (L2-hot), collect keys for s <= T_g ----------
    for (int i = 0; i < PPT; i += 4) {
        float px[4][3];
#pragma unroll
        for (int u = 0; u < 4; ++u) {
            const int n = (i + u) * TB + t;
            const float* p = base + (size_t)n * 3;
            px[u][0] = p[0]; px[u][1] = p[1]; px[u][2] = p[2];
        }
#pragma unroll
        for (int u = 0; u < 4; ++u) {
            const int n = (i + u) * TB + t;
            const float x0 = px[u][0], x1 = px[u][1], x2 = px[u][2];
            const float xs = __builtin_fmaf(x2, x2, __builtin_fmaf(x1, x1, x0 * x0));
            const f32x2 X0 = (f32x2){ x0, x0 };
            const f32x2 X1 = (f32x2){ x1, x1 };
            const f32x2 X2 = (f32x2){ x2, x2 };
            const f32x2 XS = (f32x2){ xs, xs };
#pragma unroll
            for (int p = 0; p < GB / 2; ++p) {
                const f32x2 s = C0[p] * X0 + (C1[p] * X1 + (C2[p] * X2 + XS));
                if (s.x <= T2[p].x) {
                    unsigned uu = __float_as_uint(s.x);
                    uu ^= (unsigned)(((int)uu) >> 31) | 0x80000000u;
                    const int pos = atomicAdd(&s_cnt[2 * p], 1);
                    if (pos < CAP)
                        s_cand[2 * p][pos] = ((unsigned long long)uu << 32) | (unsigned)n;
                }
                if (s.y <= T2[p].y) {
                    unsigned uu = __float_as_uint(s.y);
                    uu ^= (unsigned)(((int)uu) >> 31) | 0x80000000u;
                    const int pos = atomicAdd(&s_cnt[2 * p + 1], 1);
                    if (pos < CAP)
                        s_cand[2 * p + 1][pos] = ((unsigned long long)uu << 32) | (unsigned)n;
                }
            }
        }
    }
    __syncthreads();                                   // barrier 2

    // ---- Ranking: wave w handles group w --------------------------------
    {
        const int q = w;
        const int cnt = s_cnt[q];
        const float Tq = (q & 1) ? T2[q >> 1].y : T2[q >> 1].x;
        const float a0 = (q & 1) ? C0[q >> 1].y : C0[q >> 1].x;
        const float a1 = (q & 1) ? C1[q >> 1].y : C1[q >> 1].x;
        const float a2 = (q & 1) ? C2[q >> 1].y : C2[q >> 1].x;
        (void)Tq;
        if (cnt <= CAP) {
            // counting sort (keys unique; broadcast inner reads)
            for (int j = lane; j < cnt; j += 64) {
                const unsigned long long c = s_cand[q][j];
                int r = 0;
                for (int i = 0; i < cnt; ++i) r += (s_cand[q][i] < c) ? 1 : 0;
                if (r < GSZ) s_win[q][r] = (unsigned)c & 0xFFFFu;
            }
        } else {
            // Wave-parallel exact fallback (statistically unreachable).
            unsigned long long last = 0ull;
            for (int k = 0; k < GSZ; ++k) {
                unsigned long long best = ~0ull;
                for (int n = lane; n < NPTS; n += 64) {
                    const float x0 = base[n * 3 + 0];
                    const float x1 = base[n * 3 + 1];
                    const float x2 = base[n * 3 + 2];
                    const float xs = __builtin_fmaf(x2, x2,
                                     __builtin_fmaf(x1, x1, x0 * x0));
                    const float s = __builtin_fmaf(a0, x0,
                                    __builtin_fmaf(a1, x1,
                                    __builtin_fmaf(a2, x2, xs)));
                    unsigned uu = __float_as_uint(s);
                    uu ^= (unsigned)(((int)uu) >> 31) | 0x80000000u;
                    const unsigned long long kk =
                        ((unsigned long long)uu << 32) | (unsigned)n;
                    if (kk > last && kk < best) best = kk;
                }
#pragma unroll
                for (int mm = 32; mm >= 1; mm >>= 1) {
                    const unsigned long long o = __shfl_xor(best, mm, 64);
                    best = (o < best) ? o : best;
                }
                last = best;
                if (lane == 0) s_win[q][k] = (unsigned)best & 0xFFFFu;
            }
        }
    }
    __syncthreads();                                   // barrier 3

    // ---- Outputs --------------------------------------------------------
    const int gbase = b * 512 + g0;
    if (t < GB * GSZ) {                       // 256 threads: neighborhoods
        const int q  = t >> 5;
        const int tt = t & 31;
        const int nc = (g0 + q) * 32;
        const float cc0 = base[nc * 3 + 0];
        const float cc1 = base[nc * 3 + 1];
        const float cc2 = base[nc * 3 + 2];
        const unsigned n = s_win[q][tt];
        const float x0 = base[n * 3 + 0];
        const float x1 = base[n * 3 + 1];
        const float x2 = base[n * 3 + 2];
        const size_t ob = (((size_t)(gbase + q)) * GSZ + tt) * 3;
        out_nb[ob + 0] = x0 - cc0;
        out_nb[ob + 1] = x1 - cc1;
        out_nb[ob + 2] = x2 - cc2;
    } else if (t < GB * GSZ + GB * 3) {       // 24 threads: centers
        const int u = t - GB * GSZ;
        const int q = u / 3, c = u % 3;
        out_ctr[(size_t)(gbase + q) * 3 + c] = base[((g0 + q) * 32) * 3 + c];
    } else if (t < GB * GSZ + GB * 3 + GB) {  // 8 threads: ids
        const int q = t - (GB * GSZ + GB * 3);
        out_ids[gbase + q] = (float)((g0 + q) * 32);
    }
}

extern "C" void kernel_launch(void* const* d_in, const int* in_sizes, int n_in,
                              void* d_out, int out_size, void* d_ws, size_t ws_size,
                              hipStream_t stream) {
    const float* xyz = (const float*)d_in[0];
    float* out = (float*)d_out;
    float* out_nb  = out;                        // 786432
    float* out_ctr = out + 786432;               // 24576
    float* out_ids = out + 786432 + 24576;       // 8192
    hipLaunchKernelGGL(group_knn_kernel, dim3(16 * 512 / GB), dim3(TB), 0, stream,
                       xyz, out_nb, out_ctr, out_ids);
}